// Round 16
// baseline (650.117 us; speedup 1.0000x reference)
//
#include <hip/hip_runtime.h>

#define NN 30000
#define EE 300000
#define HD 128
#define D9 144

typedef unsigned int uint32;
typedef unsigned short u16;
typedef __attribute__((ext_vector_type(8))) short short8;
typedef __attribute__((ext_vector_type(4))) float f32x4;
typedef __attribute__((ext_vector_type(4))) uint32 u32x4;

// fast sigmoid/silu via v_rcp_f32 (rel err ~1e-5)
__device__ __forceinline__ float sigmoidf_(float x){ return __builtin_amdgcn_rcpf(1.0f + __expf(-x)); }
__device__ __forceinline__ float siluf_(float x){ return x * __builtin_amdgcn_rcpf(1.0f + __expf(-x)); }
__device__ __forceinline__ u16 f2bf(float f){
  uint32 u = __float_as_uint(f);
  return (u16)((u + 0x7fffu + ((u>>16)&1u)) >> 16);   // RNE
}
__device__ __forceinline__ float bf2f(u16 b){ return __uint_as_float(((uint32)b)<<16); }
__device__ __forceinline__ float bflo(uint32 u){ return __uint_as_float(u<<16); }
__device__ __forceinline__ float bfhi(uint32 u){ return __uint_as_float(u & 0xffff0000u); }
__device__ __forceinline__ uint32 pk2(float a, float b){ return (uint32)f2bf(a) | ((uint32)f2bf(b)<<16); }

// ---------------- fused converter + hist: Wq | W1s | W2s | gt/bet | hist ----------------
__global__ __launch_bounds__(256) void cvt_all_k(
    const float* __restrict__ Wi, u16* __restrict__ Wq,
    const float* __restrict__ W1, u16* __restrict__ W1s,
    const float* __restrict__ W2, u16* __restrict__ W2s,
    const float* __restrict__ gi, const float* __restrict__ bei,
    float* __restrict__ gt, float* __restrict__ bet,
    const int* __restrict__ ei, uint32* __restrict__ start)
{
  int i = blockIdx.x*256 + threadIdx.x;
  if (i < 512*128){
    int n = i >> 7, k = i & 127;
    float xl = Wi[n*256 + k];
    float xr = Wi[n*256 + 128 + k];
    u16 lh = f2bf(xl);
    Wq[i]          = lh;
    Wq[65536 + i]  = f2bf(xl - bf2f(lh));
    u16 rh = f2bf(xr);
    Wq[131072 + i] = rh;
    Wq[196608 + i] = f2bf(xr - bf2f(rh));
  }
  if (i < 144*128){
    float x = W1[i];
    u16 hh = f2bf(x);
    W1s[i] = hh;
    W1s[18432 + i] = f2bf(x - bf2f(hh));
  }
  if (i < 144*160){
    int r = i / 160, k = i - r*160;
    float x = (k < 144) ? W2[r*144 + k] : 0.f;
    u16 hh = f2bf(x);
    W2s[i] = hh;
    W2s[23040 + i] = f2bf(x - bf2f(hh));
  }
  if (i < 512){
    int c = i & 15, k = i >> 4;
    gt [c*32 + k] = gi[i];
    bet[c*32 + k] = bei[i];
  }
  // histogram of col (fused; start must be pre-zeroed)
  if (i < EE){
    int col = ei[EE + i];
    col = col < 0 ? 0 : (col >= NN ? NN-1 : col);
    atomicAdd(&start[col], 1u);
  }
}

// ---------------- CSR build: scan -> scatter ----------------
__global__ __launch_bounds__(1024) void scan_k(uint32* __restrict__ start){
  __shared__ uint32 part[1024];
  const int t = threadIdx.x;
  const int base = t * 30;
  uint32 loc[30];
  uint32 s = 0;
  #pragma unroll
  for (int i = 0; i < 30; ++i){
    int idx = base + i;
    uint32 cv = (idx < NN) ? start[idx] : 0u;
    loc[i] = s;
    s += cv;
  }
  part[t] = s;
  __syncthreads();
  for (int off = 1; off < 1024; off <<= 1){
    uint32 add = (t >= off) ? part[t - off] : 0u;
    __syncthreads();
    part[t] += add;
    __syncthreads();
  }
  uint32 pre = (t == 0) ? 0u : part[t - 1];
  #pragma unroll
  for (int i = 0; i < 30; ++i){
    int idx = base + i;
    if (idx < NN) start[idx] = pre + loc[i];
  }
}

__global__ __launch_bounds__(256) void scatter_k(const int* __restrict__ ei,
                                                 uint32* __restrict__ start,
                                                 u16* __restrict__ srow, u16* __restrict__ scol){
  int e = blockIdx.x*256 + threadIdx.x;
  if (e < EE){
    int row = ei[e];
    row = row < 0 ? 0 : (row >= NN ? NN-1 : row);
    int col = ei[EE + e];
    col = col < 0 ? 0 : (col >= NN ? NN-1 : col);
    uint32 pos = atomicAdd(&start[col], 1u);   // start becomes end(col)
    srow[pos] = (u16)row;
    scol[pos] = (u16)col;
  }
}

// ---------------- node_all: fused u/v GEMM + tensor_init (nt outputs) ----------------
__global__ __launch_bounds__(256) void node_all_k(
    const float* __restrict__ h, const u16* __restrict__ Wq,
    const float* __restrict__ bi,
    const u16* __restrict__ W1s, const u16* __restrict__ W2s,
    const float* __restrict__ b1, const float* __restrict__ g1, const float* __restrict__ be1,
    const float* __restrict__ b2, const float* __restrict__ g2, const float* __restrict__ be2,
    u16* __restrict__ uu_t, u16* __restrict__ v16_t, float* __restrict__ tens_t)
{
  __shared__ float t1s[16 * 164];
  __shared__ float pool[160];

  const int t = threadIdx.x;
  const int w = t >> 6, l = t & 63, lr = l & 15, lg = l >> 4;
  const int nb = blockIdx.x * 16;
  const int ntile = (w == 0) ? 3 : 2;
  int tiles[3]; tiles[0] = 2*w; tiles[1] = 2*w + 1; tiles[2] = 8;

  short8 aH[4], aL[4];
  {
    const float* qA = h + (size_t)(nb + lr) * HD + lg*8;
    #pragma unroll
    for (int ks = 0; ks < 4; ++ks){
      float4 x0 = *(const float4*)(qA + ks*32);
      float4 x1 = *(const float4*)(qA + ks*32 + 4);
      float xs[8] = {x0.x, x0.y, x0.z, x0.w, x1.x, x1.y, x1.z, x1.w};
      #pragma unroll
      for (int j = 0; j < 8; ++j){
        u16 hh = f2bf(xs[j]);
        aH[ks][j] = (short)hh;
        aL[ks][j] = (short)f2bf(xs[j] - bf2f(hh));
      }
    }
  }

  // ================= part 1: u = WiL@h + bi, v = WiR@h =================
  {
    f32x4 au[8], av[8];
    #pragma unroll
    for (int nt = 0; nt < 8; ++nt){ au[nt] = (f32x4){0,0,0,0}; av[nt] = (f32x4){0,0,0,0}; }
    #pragma unroll
    for (int ks = 0; ks < 4; ++ks){
      #pragma unroll
      for (int nt = 0; nt < 8; ++nt){
        const u16* bu = Wq + (w*128 + nt*16 + lr)*128 + lg*8 + ks*32;
        short8 bH = *(const short8*)bu;
        short8 bL = *(const short8*)(bu + 65536);
        au[nt] = __builtin_amdgcn_mfma_f32_16x16x32_bf16(aH[ks], bH, au[nt], 0, 0, 0);
        au[nt] = __builtin_amdgcn_mfma_f32_16x16x32_bf16(aL[ks], bH, au[nt], 0, 0, 0);
        au[nt] = __builtin_amdgcn_mfma_f32_16x16x32_bf16(aH[ks], bL, au[nt], 0, 0, 0);
        const u16* bv = bu + 131072;
        short8 cH = *(const short8*)bv;
        short8 cL = *(const short8*)(bv + 65536);
        av[nt] = __builtin_amdgcn_mfma_f32_16x16x32_bf16(aH[ks], cH, av[nt], 0, 0, 0);
        av[nt] = __builtin_amdgcn_mfma_f32_16x16x32_bf16(aL[ks], cH, av[nt], 0, 0, 0);
        av[nt] = __builtin_amdgcn_mfma_f32_16x16x32_bf16(aH[ks], cL, av[nt], 0, 0, 0);
      }
    }
    float bb[8];
    #pragma unroll
    for (int nt = 0; nt < 8; ++nt) bb[nt] = bi[w*128 + nt*16 + lr];
    #pragma unroll
    for (int r = 0; r < 4; ++r){
      size_t node = nb + lg*4 + r;
      u32x4 pu;
      pu.x = pk2(au[0][r]+bb[0], au[1][r]+bb[1]);
      pu.y = pk2(au[2][r]+bb[2], au[3][r]+bb[3]);
      pu.z = pk2(au[4][r]+bb[4], au[5][r]+bb[5]);
      pu.w = pk2(au[6][r]+bb[6], au[7][r]+bb[7]);
      __builtin_nontemporal_store(pu, (u32x4*)(uu_t + node*512 + lr*32 + w*8));
      u32x4 pv;
      pv.x = pk2(av[0][r], av[1][r]); pv.y = pk2(av[2][r], av[3][r]);
      pv.z = pk2(av[4][r], av[5][r]); pv.w = pk2(av[6][r], av[7][r]);
      __builtin_nontemporal_store(pv, (u32x4*)(v16_t + node*512 + lr*32 + w*8));
    }
  }

  // ================= part 2: tensor_init layer 1 =================
  f32x4 acc[3];
  #pragma unroll
  for (int ti = 0; ti < 3; ++ti) acc[ti] = (f32x4){0,0,0,0};
  #pragma unroll
  for (int ks = 0; ks < 4; ++ks){
    for (int ti = 0; ti < ntile; ++ti){
      const u16* b = W1s + (tiles[ti]*16 + lr)*128 + lg*8 + ks*32;
      short8 bH = *(const short8*)b;
      short8 bL = *(const short8*)(b + 18432);
      acc[ti] = __builtin_amdgcn_mfma_f32_16x16x32_bf16(aH[ks], bH, acc[ti], 0, 0, 0);
      acc[ti] = __builtin_amdgcn_mfma_f32_16x16x32_bf16(aL[ks], bH, acc[ti], 0, 0, 0);
      acc[ti] = __builtin_amdgcn_mfma_f32_16x16x32_bf16(aH[ks], bL, acc[ti], 0, 0, 0);
    }
  }
  for (int ti = 0; ti < ntile; ++ti){
    float bb = b1[tiles[ti]*16 + lr];
    #pragma unroll
    for (int r = 0; r < 4; ++r) acc[ti][r] += bb;
  }
  {
    float ps[4], pq[4];
    #pragma unroll
    for (int r = 0; r < 4; ++r){
      float s = 0.f, q = 0.f;
      for (int ti = 0; ti < ntile; ++ti){ s += acc[ti][r]; q += acc[ti][r]*acc[ti][r]; }
      ps[r] = s; pq[r] = q;
    }
    #pragma unroll
    for (int off = 1; off < 16; off <<= 1)
      #pragma unroll
      for (int r = 0; r < 4; ++r){ ps[r] += __shfl_xor(ps[r], off); pq[r] += __shfl_xor(pq[r], off); }
    if (lr == 0){
      #pragma unroll
      for (int r = 0; r < 4; ++r){
        pool[w*32 + (lg*4 + r)*2 + 0] = ps[r];
        pool[w*32 + (lg*4 + r)*2 + 1] = pq[r];
      }
    }
  }
  __syncthreads();
  if (t < 16){
    float s = pool[t*2] + pool[32 + t*2] + pool[64 + t*2] + pool[96 + t*2];
    float q = pool[t*2+1] + pool[32 + t*2+1] + pool[64 + t*2+1] + pool[96 + t*2+1];
    float mu = s * (1.0f/144.0f);
    pool[128 + t] = mu;
    pool[144 + t] = rsqrtf(q * (1.0f/144.0f) - mu*mu + 1e-5f);
  }
  __syncthreads();
  for (int ti = 0; ti < ntile; ++ti){
    int col = tiles[ti]*16 + lr;
    float gg = g1[col], bb = be1[col];
    #pragma unroll
    for (int r = 0; r < 4; ++r){
      int node = lg*4 + r;
      float mu = pool[128 + node], rs = pool[144 + node];
      t1s[node*164 + col] = siluf_((acc[ti][r] - mu) * rs * gg + bb);
    }
  }
  t1s[(t >> 4)*164 + 144 + (t & 15)] = 0.f;
  __syncthreads();

  // ================= layer 2 (K=160 padded) =================
  #pragma unroll
  for (int ti = 0; ti < 3; ++ti) acc[ti] = (f32x4){0,0,0,0};
  #pragma unroll
  for (int ks = 0; ks < 5; ++ks){
    float4 x0 = *(const float4*)&t1s[lr*164 + lg*8 + ks*32];
    float4 x1 = *(const float4*)&t1s[lr*164 + lg*8 + ks*32 + 4];
    float xs[8] = {x0.x, x0.y, x0.z, x0.w, x1.x, x1.y, x1.z, x1.w};
    short8 a2H, a2L;
    #pragma unroll
    for (int j = 0; j < 8; ++j){
      u16 hh = f2bf(xs[j]);
      a2H[j] = (short)hh;
      a2L[j] = (short)f2bf(xs[j] - bf2f(hh));
    }
    for (int ti = 0; ti < ntile; ++ti){
      const u16* b = W2s + (tiles[ti]*16 + lr)*160 + lg*8 + ks*32;
      short8 bH = *(const short8*)b;
      short8 bL = *(const short8*)(b + 23040);
      acc[ti] = __builtin_amdgcn_mfma_f32_16x16x32_bf16(a2H, bH, acc[ti], 0, 0, 0);
      acc[ti] = __builtin_amdgcn_mfma_f32_16x16x32_bf16(a2L, bH, acc[ti], 0, 0, 0);
      acc[ti] = __builtin_amdgcn_mfma_f32_16x16x32_bf16(a2H, bL, acc[ti], 0, 0, 0);
    }
  }
  for (int ti = 0; ti < ntile; ++ti){
    float bb = b2[tiles[ti]*16 + lr];
    #pragma unroll
    for (int r = 0; r < 4; ++r) acc[ti][r] += bb;
  }
  __syncthreads();
  {
    float ps[4], pq[4];
    #pragma unroll
    for (int r = 0; r < 4; ++r){
      float s = 0.f, q = 0.f;
      for (int ti = 0; ti < ntile; ++ti){ s += acc[ti][r]; q += acc[ti][r]*acc[ti][r]; }
      ps[r] = s; pq[r] = q;
    }
    #pragma unroll
    for (int off = 1; off < 16; off <<= 1)
      #pragma unroll
      for (int r = 0; r < 4; ++r){ ps[r] += __shfl_xor(ps[r], off); pq[r] += __shfl_xor(pq[r], off); }
    if (lr == 0){
      #pragma unroll
      for (int r = 0; r < 4; ++r){
        pool[w*32 + (lg*4 + r)*2 + 0] = ps[r];
        pool[w*32 + (lg*4 + r)*2 + 1] = pq[r];
      }
    }
  }
  __syncthreads();
  if (t < 16){
    float s = pool[t*2] + pool[32 + t*2] + pool[64 + t*2] + pool[96 + t*2];
    float q = pool[t*2+1] + pool[32 + t*2+1] + pool[64 + t*2+1] + pool[96 + t*2+1];
    float mu = s * (1.0f/144.0f);
    pool[128 + t] = mu;
    pool[144 + t] = rsqrtf(q * (1.0f/144.0f) - mu*mu + 1e-5f);
  }
  __syncthreads();
  for (int ti = 0; ti < ntile; ++ti){
    int col = tiles[ti]*16 + lr;
    float gg = g2[col], bb = be2[col];
    int c = col / 9, m = col - c*9;
    #pragma unroll
    for (int r = 0; r < 4; ++r){
      int node = lg*4 + r;
      float mu = pool[128 + node], rs = pool[144 + node];
      float val = siluf_((acc[ti][r] - mu) * rs * gg + bb);
      __builtin_nontemporal_store(val, tens_t + (size_t)(nb + node)*144 + m*16 + c);
    }
  }
}

// ---------------- edge_par: 32 lanes per edge; nt stores for tn ----------------
__global__ __launch_bounds__(256) void edge_par_k(
    const u16* __restrict__ uu_t, const u16* __restrict__ v16_t,
    const float* __restrict__ frames, const float* __restrict__ tens_t,
    const float* __restrict__ gt, const float* __restrict__ bet,
    const u16* __restrict__ srow, const u16* __restrict__ scol,
    uint32* __restrict__ tn)
{
  const int t  = threadIdx.x;
  const int le = t >> 5;          // edge within block (8)
  const int hf = (t >> 4) & 1;    // half: 0 -> k in [0,16), 1 -> k in [16,32)
  const int c  = t & 15;          // channel
  const int e  = blockIdx.x*8 + le;
  const int row = (int)srow[e], col = (int)scol[e];

  // ---- z[j] = u[col][c, hf*16+j] + v[row][c, hf*16+j] ----
  float z[16];
  {
    const u16* up = uu_t  + (size_t)col*512 + c*32 + hf*16;
    const u16* vp = v16_t + (size_t)row*512 + c*32 + hf*16;
    #pragma unroll
    for (int q = 0; q < 2; ++q){
      u32x4 ua = *(const u32x4*)(up + q*8);
      u32x4 va = *(const u32x4*)(vp + q*8);
      z[q*8+0] = bflo(ua.x)+bflo(va.x); z[q*8+1] = bfhi(ua.x)+bfhi(va.x);
      z[q*8+2] = bflo(ua.y)+bflo(va.y); z[q*8+3] = bfhi(ua.y)+bfhi(va.y);
      z[q*8+4] = bflo(ua.z)+bflo(va.z); z[q*8+5] = bfhi(ua.z)+bfhi(va.z);
      z[q*8+6] = bflo(ua.w)+bflo(va.w); z[q*8+7] = bfhi(ua.w)+bfhi(va.w);
    }
  }

  // ---- LN over 512 (16/lane x 32 lanes of this edge) ----
  float s = 0.f, q2 = 0.f;
  #pragma unroll
  for (int k = 0; k < 16; ++k){ s += z[k]; q2 += z[k]*z[k]; }
  #pragma unroll
  for (int off = 1; off < 32; off <<= 1){ s += __shfl_xor(s, off); q2 += __shfl_xor(q2, off); }
  float mu = s * (1.0f/512.0f);
  float rs = rsqrtf(q2 * (1.0f/512.0f) - mu*mu + 1e-5f);

  // ---- w = sigmoid(LN(z)) for this half's 16 k's ----
  {
    const float* gp = gt  + c*32 + hf*16;
    const float* bp = bet + c*32 + hf*16;
    #pragma unroll
    for (int kq = 0; kq < 4; ++kq){
      float4 g4 = *(const float4*)(gp + kq*4);
      float4 b4 = *(const float4*)(bp + kq*4);
      z[kq*4+0] = sigmoidf_((z[kq*4+0]-mu)*rs*g4.x + b4.x);
      z[kq*4+1] = sigmoidf_((z[kq*4+1]-mu)*rs*g4.y + b4.y);
      z[kq*4+2] = sigmoidf_((z[kq*4+2]-mu)*rs*g4.z + b4.z);
      z[kq*4+3] = sigmoidf_((z[kq*4+3]-mu)*rs*g4.w + b4.w);
    }
  }

  // ---- contraction: P[m] = sum_j T[m*16+j] * w[j]; T = ti (half 0) or tj (half 1) ----
  float P[9];
  {
    const float* T = tens_t + (size_t)(hf ? row : col) * 144;
    #pragma unroll
    for (int m = 0; m < 9; ++m){
      float4 a0 = *(const float4*)(T + m*16);
      float4 a1 = *(const float4*)(T + m*16 + 4);
      float4 a2 = *(const float4*)(T + m*16 + 8);
      float4 a3 = *(const float4*)(T + m*16 + 12);
      P[m] = a0.x*z[0]  + a0.y*z[1]  + a0.z*z[2]  + a0.w*z[3]
           + a1.x*z[4]  + a1.y*z[5]  + a1.z*z[6]  + a1.w*z[7]
           + a2.x*z[8]  + a2.y*z[9]  + a2.z*z[10] + a2.w*z[11]
           + a3.x*z[12] + a3.y*z[13] + a3.z*z[14] + a3.w*z[15];
    }
  }

  // ---- half 1: rotate P -> R P R (R = Ri^T Rj) ----
  if (hf){
    const float* Ri = frames + (size_t)col*9;
    const float* Rj = frames + (size_t)row*9;
    float R[9];
    #pragma unroll
    for (int i = 0; i < 3; ++i)
      #pragma unroll
      for (int j = 0; j < 3; ++j)
        R[i*3+j] = Ri[i]*Rj[j] + Ri[3+i]*Rj[3+j] + Ri[6+i]*Rj[6+j];
    float A[9];
    #pragma unroll
    for (int i = 0; i < 3; ++i)
      #pragma unroll
      for (int j = 0; j < 3; ++j)
        A[i*3+j] = R[i*3+0]*P[0+j] + R[i*3+1]*P[3+j] + R[i*3+2]*P[6+j];
    #pragma unroll
    for (int i = 0; i < 3; ++i)
      #pragma unroll
      for (int j = 0; j < 3; ++j)
        P[i*3+j] = A[i*3+0]*R[0+j] + A[i*3+1]*R[3+j] + A[i*3+2]*R[6+j];
  }

  // ---- combine halves: o = P_half0 + P_half1 ----
  #pragma unroll
  for (int m = 0; m < 9; ++m) P[m] += __shfl_xor(P[m], 16);

  if (hf == 0){
    float s01 = 0.5f*(P[1]+P[3]), s02 = 0.5f*(P[2]+P[6]), s12 = 0.5f*(P[5]+P[7]);
    uint32* tp = tn + (size_t)e*48 + c*3;
    __builtin_nontemporal_store(pk2(P[0], s01), tp + 0);
    __builtin_nontemporal_store(pk2(s02, P[4]), tp + 1);
    __builtin_nontemporal_store(pk2(s12, P[8]), tp + 2);
  }
}

// ---------------- segsum: thread per (node, channel); nt loads; 2x unroll ----------------
__global__ __launch_bounds__(256) void segsum_k(
    const uint32* __restrict__ tn, const uint32* __restrict__ start,
    float* __restrict__ out)
{
  int tid = blockIdx.x*256 + threadIdx.x;
  if (tid >= NN*16) return;
  int n = tid >> 4, c = tid & 15;
  uint32 beg = (n == 0) ? 0u : start[n-1];
  uint32 end = start[n];

  float a0=0.f, a1=0.f, a2=0.f, a3=0.f, a4=0.f, a5=0.f;
  uint32 i = beg;
  for (; i + 2 <= end; i += 2){
    const uint32* tp0 = tn + (size_t)i*48 + c*3;
    const uint32* tp1 = tn + (size_t)(i+1)*48 + c*3;
    uint32 x0 = __builtin_nontemporal_load(tp0 + 0);
    uint32 x1 = __builtin_nontemporal_load(tp0 + 1);
    uint32 x2 = __builtin_nontemporal_load(tp0 + 2);
    uint32 y0 = __builtin_nontemporal_load(tp1 + 0);
    uint32 y1 = __builtin_nontemporal_load(tp1 + 1);
    uint32 y2 = __builtin_nontemporal_load(tp1 + 2);
    a0 += bflo(x0) + bflo(y0); a1 += bfhi(x0) + bfhi(y0);
    a2 += bflo(x1) + bflo(y1); a3 += bfhi(x1) + bfhi(y1);
    a4 += bflo(x2) + bflo(y2); a5 += bfhi(x2) + bfhi(y2);
  }
  if (i < end){
    const uint32* tp = tn + (size_t)i*48 + c*3;
    uint32 x0 = __builtin_nontemporal_load(tp + 0);
    uint32 x1 = __builtin_nontemporal_load(tp + 1);
    uint32 x2 = __builtin_nontemporal_load(tp + 2);
    a0 += bflo(x0); a1 += bfhi(x0);
    a2 += bflo(x1); a3 += bfhi(x1);
    a4 += bflo(x2); a5 += bfhi(x2);
  }

  float* op = out + (size_t)n*144 + c*9;
  __builtin_nontemporal_store(a0, op + 0);
  __builtin_nontemporal_store(a1, op + 1);
  __builtin_nontemporal_store(a2, op + 2);
  __builtin_nontemporal_store(a1, op + 3);
  __builtin_nontemporal_store(a3, op + 4);
  __builtin_nontemporal_store(a4, op + 5);
  __builtin_nontemporal_store(a2, op + 6);
  __builtin_nontemporal_store(a4, op + 7);
  __builtin_nontemporal_store(a5, op + 8);
}

extern "C" void kernel_launch(void* const* d_in, const int* in_sizes, int n_in,
                              void* d_out, int out_size, void* d_ws, size_t ws_size,
                              hipStream_t stream) {
    const float* h      = (const float*)d_in[1];
    const float* frames = (const float*)d_in[2];
    const int*   ei     = (const int*)d_in[3];
    const float* W1  = (const float*)d_in[5];
    const float* b1  = (const float*)d_in[6];
    const float* g1  = (const float*)d_in[7];
    const float* be1 = (const float*)d_in[8];
    const float* W2  = (const float*)d_in[9];
    const float* b2  = (const float*)d_in[10];
    const float* g2  = (const float*)d_in[11];
    const float* be2 = (const float*)d_in[12];
    const float* Wi  = (const float*)d_in[13];
    const float* bi  = (const float*)d_in[14];
    const float* gi  = (const float*)d_in[15];
    const float* bei = (const float*)d_in[16];

    float* out = (float*)d_out;

    // ws layout (138.33 MB <= proven 140.68 MB):
    u16*    uu_t  = (u16*)d_ws;                             // [N,512] bf16: 30,720,000
    u16*    v16_t = (u16*)  ((char*)d_ws + 30720000);       // [N,512] bf16: 30,720,000
    float*  tens_t= (float*)((char*)d_ws + 61440000);       // [N,144] f32 : 17,280,000
    u16*    Wq    = (u16*)  ((char*)d_ws + 78720000);       // 524,288
    u16*    W1s   = (u16*)  ((char*)d_ws + 79244288);       // 73,728
    u16*    W2s   = (u16*)  ((char*)d_ws + 79318016);       // 92,160
    float*  gt    = (float*)((char*)d_ws + 79410176);       // 2,048
    float*  bet   = (float*)((char*)d_ws + 79412224);       // 2,048
    uint32* start = (uint32*)((char*)d_ws + 79414272);      // 120,000
    u16*    srow  = (u16*)  ((char*)d_ws + 79534272);       // 600,000
    u16*    scol  = (u16*)  ((char*)d_ws + 80134272);       // 600,000
    uint32* tn    = (uint32*)((char*)d_ws + 80734272);      // [E,16,3] u32 (bf16x2): 57,600,000

    hipMemsetAsync(start, 0, NN * sizeof(uint32), stream);

    cvt_all_k<<<(EE + 255)/256, 256, 0, stream>>>(Wi, Wq, W1, W1s, W2, W2s, gi, bei, gt, bet,
                                                  ei, start);
    node_all_k<<<NN/16, 256, 0, stream>>>(h, Wq, bi, W1s, W2s, b1, g1, be1, b2, g2, be2,
                                          uu_t, v16_t, tens_t);
    scan_k<<<1, 1024, 0, stream>>>(start);
    scatter_k<<<(EE + 255)/256, 256, 0, stream>>>(ei, start, srow, scol);
    edge_par_k<<<EE/8, 256, 0, stream>>>(uu_t, v16_t, frames, tens_t, gt, bet, srow, scol, tn);
    segsum_k<<<(NN*16 + 255)/256, 256, 0, stream>>>(tn, start, out);
}

// Round 17
// 610.899 us; speedup vs baseline: 1.0642x; 1.0642x over previous
//
#include <hip/hip_runtime.h>

#define NN 30000
#define EE 300000
#define HD 128
#define D9 144

typedef unsigned int uint32;
typedef unsigned short u16;
typedef __attribute__((ext_vector_type(8))) short short8;
typedef __attribute__((ext_vector_type(4))) float f32x4;
typedef __attribute__((ext_vector_type(4))) uint32 u32x4;

// fast sigmoid/silu via v_rcp_f32 (rel err ~1e-5)
__device__ __forceinline__ float sigmoidf_(float x){ return __builtin_amdgcn_rcpf(1.0f + __expf(-x)); }
__device__ __forceinline__ float siluf_(float x){ return x * __builtin_amdgcn_rcpf(1.0f + __expf(-x)); }
__device__ __forceinline__ u16 f2bf(float f){
  uint32 u = __float_as_uint(f);
  return (u16)((u + 0x7fffu + ((u>>16)&1u)) >> 16);   // RNE
}
__device__ __forceinline__ float bf2f(u16 b){ return __uint_as_float(((uint32)b)<<16); }
__device__ __forceinline__ float bflo(uint32 u){ return __uint_as_float(u<<16); }
__device__ __forceinline__ float bfhi(uint32 u){ return __uint_as_float(u & 0xffff0000u); }
__device__ __forceinline__ uint32 pk2(float a, float b){ return (uint32)f2bf(a) | ((uint32)f2bf(b)<<16); }

// ---------------- fused converter: Wq | W1s | W2s | gt/bet ----------------
__global__ __launch_bounds__(256) void cvt_all_k(
    const float* __restrict__ Wi, u16* __restrict__ Wq,
    const float* __restrict__ W1, u16* __restrict__ W1s,
    const float* __restrict__ W2, u16* __restrict__ W2s,
    const float* __restrict__ gi, const float* __restrict__ bei,
    float* __restrict__ gt, float* __restrict__ bet)
{
  int i = blockIdx.x*256 + threadIdx.x;
  if (i < 512*128){
    int n = i >> 7, k = i & 127;
    float xl = Wi[n*256 + k];
    float xr = Wi[n*256 + 128 + k];
    u16 lh = f2bf(xl);
    Wq[i]          = lh;
    Wq[65536 + i]  = f2bf(xl - bf2f(lh));
    u16 rh = f2bf(xr);
    Wq[131072 + i] = rh;
    Wq[196608 + i] = f2bf(xr - bf2f(rh));
  }
  if (i < 144*128){
    float x = W1[i];
    u16 hh = f2bf(x);
    W1s[i] = hh;
    W1s[18432 + i] = f2bf(x - bf2f(hh));
  }
  if (i < 144*160){
    int r = i / 160, k = i - r*160;
    float x = (k < 144) ? W2[r*144 + k] : 0.f;
    u16 hh = f2bf(x);
    W2s[i] = hh;
    W2s[23040 + i] = f2bf(x - bf2f(hh));
  }
  if (i < 512){
    int c = i & 15, k = i >> 4;
    gt [c*32 + k] = gi[i];
    bet[c*32 + k] = bei[i];
  }
}

// ---------------- CSR build: hist -> scan -> scatter ----------------
__global__ __launch_bounds__(256) void hist_k(const int* __restrict__ ei, uint32* __restrict__ start){
  int e = blockIdx.x*256 + threadIdx.x;
  if (e < EE){
    int col = ei[EE + e];
    col = col < 0 ? 0 : (col >= NN ? NN-1 : col);
    atomicAdd(&start[col], 1u);
  }
}

__global__ __launch_bounds__(1024) void scan_k(uint32* __restrict__ start){
  __shared__ uint32 part[1024];
  const int t = threadIdx.x;
  const int base = t * 30;
  uint32 loc[30];
  uint32 s = 0;
  #pragma unroll
  for (int i = 0; i < 30; ++i){
    int idx = base + i;
    uint32 cv = (idx < NN) ? start[idx] : 0u;
    loc[i] = s;
    s += cv;
  }
  part[t] = s;
  __syncthreads();
  for (int off = 1; off < 1024; off <<= 1){
    uint32 add = (t >= off) ? part[t - off] : 0u;
    __syncthreads();
    part[t] += add;
    __syncthreads();
  }
  uint32 pre = (t == 0) ? 0u : part[t - 1];
  #pragma unroll
  for (int i = 0; i < 30; ++i){
    int idx = base + i;
    if (idx < NN) start[idx] = pre + loc[i];
  }
}

__global__ __launch_bounds__(256) void scatter_k(const int* __restrict__ ei,
                                                 uint32* __restrict__ start,
                                                 u16* __restrict__ srow, u16* __restrict__ scol){
  int e = blockIdx.x*256 + threadIdx.x;
  if (e < EE){
    int row = ei[e];
    row = row < 0 ? 0 : (row >= NN ? NN-1 : row);
    int col = ei[EE + e];
    col = col < 0 ? 0 : (col >= NN ? NN-1 : col);
    uint32 pos = atomicAdd(&start[col], 1u);   // start becomes end(col)
    srow[pos] = (u16)row;
    scol[pos] = (u16)col;
  }
}

// ---------------- node_all: fused u/v GEMM + tensor_init (f32 tens out) ----------------
__global__ __launch_bounds__(256) void node_all_k(
    const float* __restrict__ h, const u16* __restrict__ Wq,
    const float* __restrict__ bi,
    const u16* __restrict__ W1s, const u16* __restrict__ W2s,
    const float* __restrict__ b1, const float* __restrict__ g1, const float* __restrict__ be1,
    const float* __restrict__ b2, const float* __restrict__ g2, const float* __restrict__ be2,
    u16* __restrict__ uu_t, u16* __restrict__ v16_t, float* __restrict__ tens_t)
{
  __shared__ float t1s[16 * 164];
  __shared__ float pool[160];

  const int t = threadIdx.x;
  const int w = t >> 6, l = t & 63, lr = l & 15, lg = l >> 4;
  const int nb = blockIdx.x * 16;
  const int ntile = (w == 0) ? 3 : 2;
  int tiles[3]; tiles[0] = 2*w; tiles[1] = 2*w + 1; tiles[2] = 8;

  short8 aH[4], aL[4];
  {
    const float* qA = h + (size_t)(nb + lr) * HD + lg*8;
    #pragma unroll
    for (int ks = 0; ks < 4; ++ks){
      float4 x0 = *(const float4*)(qA + ks*32);
      float4 x1 = *(const float4*)(qA + ks*32 + 4);
      float xs[8] = {x0.x, x0.y, x0.z, x0.w, x1.x, x1.y, x1.z, x1.w};
      #pragma unroll
      for (int j = 0; j < 8; ++j){
        u16 hh = f2bf(xs[j]);
        aH[ks][j] = (short)hh;
        aL[ks][j] = (short)f2bf(xs[j] - bf2f(hh));
      }
    }
  }

  // ================= part 1: u = WiL@h + bi, v = WiR@h =================
  {
    f32x4 au[8], av[8];
    #pragma unroll
    for (int nt = 0; nt < 8; ++nt){ au[nt] = (f32x4){0,0,0,0}; av[nt] = (f32x4){0,0,0,0}; }
    #pragma unroll
    for (int ks = 0; ks < 4; ++ks){
      #pragma unroll
      for (int nt = 0; nt < 8; ++nt){
        const u16* bu = Wq + (w*128 + nt*16 + lr)*128 + lg*8 + ks*32;
        short8 bH = *(const short8*)bu;
        short8 bL = *(const short8*)(bu + 65536);
        au[nt] = __builtin_amdgcn_mfma_f32_16x16x32_bf16(aH[ks], bH, au[nt], 0, 0, 0);
        au[nt] = __builtin_amdgcn_mfma_f32_16x16x32_bf16(aL[ks], bH, au[nt], 0, 0, 0);
        au[nt] = __builtin_amdgcn_mfma_f32_16x16x32_bf16(aH[ks], bL, au[nt], 0, 0, 0);
        const u16* bv = bu + 131072;
        short8 cH = *(const short8*)bv;
        short8 cL = *(const short8*)(bv + 65536);
        av[nt] = __builtin_amdgcn_mfma_f32_16x16x32_bf16(aH[ks], cH, av[nt], 0, 0, 0);
        av[nt] = __builtin_amdgcn_mfma_f32_16x16x32_bf16(aL[ks], cH, av[nt], 0, 0, 0);
        av[nt] = __builtin_amdgcn_mfma_f32_16x16x32_bf16(aH[ks], cL, av[nt], 0, 0, 0);
      }
    }
    float bb[8];
    #pragma unroll
    for (int nt = 0; nt < 8; ++nt) bb[nt] = bi[w*128 + nt*16 + lr];
    #pragma unroll
    for (int r = 0; r < 4; ++r){
      size_t node = nb + lg*4 + r;
      u32x4 pu;
      pu.x = pk2(au[0][r]+bb[0], au[1][r]+bb[1]);
      pu.y = pk2(au[2][r]+bb[2], au[3][r]+bb[3]);
      pu.z = pk2(au[4][r]+bb[4], au[5][r]+bb[5]);
      pu.w = pk2(au[6][r]+bb[6], au[7][r]+bb[7]);
      *(u32x4*)(uu_t + node*512 + lr*32 + w*8) = pu;
      u32x4 pv;
      pv.x = pk2(av[0][r], av[1][r]); pv.y = pk2(av[2][r], av[3][r]);
      pv.z = pk2(av[4][r], av[5][r]); pv.w = pk2(av[6][r], av[7][r]);
      *(u32x4*)(v16_t + node*512 + lr*32 + w*8) = pv;
    }
  }

  // ================= part 2: tensor_init layer 1 =================
  f32x4 acc[3];
  #pragma unroll
  for (int ti = 0; ti < 3; ++ti) acc[ti] = (f32x4){0,0,0,0};
  #pragma unroll
  for (int ks = 0; ks < 4; ++ks){
    for (int ti = 0; ti < ntile; ++ti){
      const u16* b = W1s + (tiles[ti]*16 + lr)*128 + lg*8 + ks*32;
      short8 bH = *(const short8*)b;
      short8 bL = *(const short8*)(b + 18432);
      acc[ti] = __builtin_amdgcn_mfma_f32_16x16x32_bf16(aH[ks], bH, acc[ti], 0, 0, 0);
      acc[ti] = __builtin_amdgcn_mfma_f32_16x16x32_bf16(aL[ks], bH, acc[ti], 0, 0, 0);
      acc[ti] = __builtin_amdgcn_mfma_f32_16x16x32_bf16(aH[ks], bL, acc[ti], 0, 0, 0);
    }
  }
  for (int ti = 0; ti < ntile; ++ti){
    float bb = b1[tiles[ti]*16 + lr];
    #pragma unroll
    for (int r = 0; r < 4; ++r) acc[ti][r] += bb;
  }
  {
    float ps[4], pq[4];
    #pragma unroll
    for (int r = 0; r < 4; ++r){
      float s = 0.f, q = 0.f;
      for (int ti = 0; ti < ntile; ++ti){ s += acc[ti][r]; q += acc[ti][r]*acc[ti][r]; }
      ps[r] = s; pq[r] = q;
    }
    #pragma unroll
    for (int off = 1; off < 16; off <<= 1)
      #pragma unroll
      for (int r = 0; r < 4; ++r){ ps[r] += __shfl_xor(ps[r], off); pq[r] += __shfl_xor(pq[r], off); }
    if (lr == 0){
      #pragma unroll
      for (int r = 0; r < 4; ++r){
        pool[w*32 + (lg*4 + r)*2 + 0] = ps[r];
        pool[w*32 + (lg*4 + r)*2 + 1] = pq[r];
      }
    }
  }
  __syncthreads();
  if (t < 16){
    float s = pool[t*2] + pool[32 + t*2] + pool[64 + t*2] + pool[96 + t*2];
    float q = pool[t*2+1] + pool[32 + t*2+1] + pool[64 + t*2+1] + pool[96 + t*2+1];
    float mu = s * (1.0f/144.0f);
    pool[128 + t] = mu;
    pool[144 + t] = rsqrtf(q * (1.0f/144.0f) - mu*mu + 1e-5f);
  }
  __syncthreads();
  for (int ti = 0; ti < ntile; ++ti){
    int col = tiles[ti]*16 + lr;
    float gg = g1[col], bb = be1[col];
    #pragma unroll
    for (int r = 0; r < 4; ++r){
      int node = lg*4 + r;
      float mu = pool[128 + node], rs = pool[144 + node];
      t1s[node*164 + col] = siluf_((acc[ti][r] - mu) * rs * gg + bb);
    }
  }
  t1s[(t >> 4)*164 + 144 + (t & 15)] = 0.f;
  __syncthreads();

  // ================= layer 2 (K=160 padded) =================
  #pragma unroll
  for (int ti = 0; ti < 3; ++ti) acc[ti] = (f32x4){0,0,0,0};
  #pragma unroll
  for (int ks = 0; ks < 5; ++ks){
    float4 x0 = *(const float4*)&t1s[lr*164 + lg*8 + ks*32];
    float4 x1 = *(const float4*)&t1s[lr*164 + lg*8 + ks*32 + 4];
    float xs[8] = {x0.x, x0.y, x0.z, x0.w, x1.x, x1.y, x1.z, x1.w};
    short8 a2H, a2L;
    #pragma unroll
    for (int j = 0; j < 8; ++j){
      u16 hh = f2bf(xs[j]);
      a2H[j] = (short)hh;
      a2L[j] = (short)f2bf(xs[j] - bf2f(hh));
    }
    for (int ti = 0; ti < ntile; ++ti){
      const u16* b = W2s + (tiles[ti]*16 + lr)*160 + lg*8 + ks*32;
      short8 bH = *(const short8*)b;
      short8 bL = *(const short8*)(b + 23040);
      acc[ti] = __builtin_amdgcn_mfma_f32_16x16x32_bf16(a2H, bH, acc[ti], 0, 0, 0);
      acc[ti] = __builtin_amdgcn_mfma_f32_16x16x32_bf16(a2L, bH, acc[ti], 0, 0, 0);
      acc[ti] = __builtin_amdgcn_mfma_f32_16x16x32_bf16(a2H, bL, acc[ti], 0, 0, 0);
    }
  }
  for (int ti = 0; ti < ntile; ++ti){
    float bb = b2[tiles[ti]*16 + lr];
    #pragma unroll
    for (int r = 0; r < 4; ++r) acc[ti][r] += bb;
  }
  __syncthreads();
  {
    float ps[4], pq[4];
    #pragma unroll
    for (int r = 0; r < 4; ++r){
      float s = 0.f, q = 0.f;
      for (int ti = 0; ti < ntile; ++ti){ s += acc[ti][r]; q += acc[ti][r]*acc[ti][r]; }
      ps[r] = s; pq[r] = q;
    }
    #pragma unroll
    for (int off = 1; off < 16; off <<= 1)
      #pragma unroll
      for (int r = 0; r < 4; ++r){ ps[r] += __shfl_xor(ps[r], off); pq[r] += __shfl_xor(pq[r], off); }
    if (lr == 0){
      #pragma unroll
      for (int r = 0; r < 4; ++r){
        pool[w*32 + (lg*4 + r)*2 + 0] = ps[r];
        pool[w*32 + (lg*4 + r)*2 + 1] = pq[r];
      }
    }
  }
  __syncthreads();
  if (t < 16){
    float s = pool[t*2] + pool[32 + t*2] + pool[64 + t*2] + pool[96 + t*2];
    float q = pool[t*2+1] + pool[32 + t*2+1] + pool[64 + t*2+1] + pool[96 + t*2+1];
    float mu = s * (1.0f/144.0f);
    pool[128 + t] = mu;
    pool[144 + t] = rsqrtf(q * (1.0f/144.0f) - mu*mu + 1e-5f);
  }
  __syncthreads();
  for (int ti = 0; ti < ntile; ++ti){
    int col = tiles[ti]*16 + lr;
    float gg = g2[col], bb = be2[col];
    int c = col / 9, m = col - c*9;
    #pragma unroll
    for (int r = 0; r < 4; ++r){
      int node = lg*4 + r;
      float mu = pool[128 + node], rs = pool[144 + node];
      float val = siluf_((acc[ti][r] - mu) * rs * gg + bb);
      tens_t[(size_t)(nb + node)*144 + m*16 + c] = val;
    }
  }
}

// ---------------- edge_par: 32 lanes per edge (half 0 = ti-part, half 1 = tj+rotation) ----------------
// 8 edges per 256-thread block; z[16] per lane; LN over 32 lanes; combine via one shfl_xor(16).
__global__ __launch_bounds__(256) void edge_par_k(
    const u16* __restrict__ uu_t, const u16* __restrict__ v16_t,
    const float* __restrict__ frames, const float* __restrict__ tens_t,
    const float* __restrict__ gt, const float* __restrict__ bet,
    const u16* __restrict__ srow, const u16* __restrict__ scol,
    uint32* __restrict__ tn)
{
  const int t  = threadIdx.x;
  const int le = t >> 5;          // edge within block (8)
  const int hf = (t >> 4) & 1;    // half: 0 -> k in [0,16), 1 -> k in [16,32)
  const int c  = t & 15;          // channel
  const int e  = blockIdx.x*8 + le;
  const int row = (int)srow[e], col = (int)scol[e];

  // ---- z[j] = u[col][c, hf*16+j] + v[row][c, hf*16+j] ----
  float z[16];
  {
    const u16* up = uu_t  + (size_t)col*512 + c*32 + hf*16;
    const u16* vp = v16_t + (size_t)row*512 + c*32 + hf*16;
    #pragma unroll
    for (int q = 0; q < 2; ++q){
      u32x4 ua = *(const u32x4*)(up + q*8);
      u32x4 va = *(const u32x4*)(vp + q*8);
      z[q*8+0] = bflo(ua.x)+bflo(va.x); z[q*8+1] = bfhi(ua.x)+bfhi(va.x);
      z[q*8+2] = bflo(ua.y)+bflo(va.y); z[q*8+3] = bfhi(ua.y)+bfhi(va.y);
      z[q*8+4] = bflo(ua.z)+bflo(va.z); z[q*8+5] = bfhi(ua.z)+bfhi(va.z);
      z[q*8+6] = bflo(ua.w)+bflo(va.w); z[q*8+7] = bfhi(ua.w)+bfhi(va.w);
    }
  }

  // ---- LN over 512 (16/lane x 32 lanes of this edge) ----
  float s = 0.f, q2 = 0.f;
  #pragma unroll
  for (int k = 0; k < 16; ++k){ s += z[k]; q2 += z[k]*z[k]; }
  #pragma unroll
  for (int off = 1; off < 32; off <<= 1){ s += __shfl_xor(s, off); q2 += __shfl_xor(q2, off); }
  float mu = s * (1.0f/512.0f);
  float rs = rsqrtf(q2 * (1.0f/512.0f) - mu*mu + 1e-5f);

  // ---- w = sigmoid(LN(z)) for this half's 16 k's ----
  {
    const float* gp = gt  + c*32 + hf*16;
    const float* bp = bet + c*32 + hf*16;
    #pragma unroll
    for (int kq = 0; kq < 4; ++kq){
      float4 g4 = *(const float4*)(gp + kq*4);
      float4 b4 = *(const float4*)(bp + kq*4);
      z[kq*4+0] = sigmoidf_((z[kq*4+0]-mu)*rs*g4.x + b4.x);
      z[kq*4+1] = sigmoidf_((z[kq*4+1]-mu)*rs*g4.y + b4.y);
      z[kq*4+2] = sigmoidf_((z[kq*4+2]-mu)*rs*g4.z + b4.z);
      z[kq*4+3] = sigmoidf_((z[kq*4+3]-mu)*rs*g4.w + b4.w);
    }
  }

  // ---- contraction: P[m] = sum_j T[m*16+j] * w[j]; T = ti (half 0) or tj (half 1) ----
  float P[9];
  {
    const float* T = tens_t + (size_t)(hf ? row : col) * 144;
    #pragma unroll
    for (int m = 0; m < 9; ++m){
      float4 a0 = *(const float4*)(T + m*16);
      float4 a1 = *(const float4*)(T + m*16 + 4);
      float4 a2 = *(const float4*)(T + m*16 + 8);
      float4 a3 = *(const float4*)(T + m*16 + 12);
      P[m] = a0.x*z[0]  + a0.y*z[1]  + a0.z*z[2]  + a0.w*z[3]
           + a1.x*z[4]  + a1.y*z[5]  + a1.z*z[6]  + a1.w*z[7]
           + a2.x*z[8]  + a2.y*z[9]  + a2.z*z[10] + a2.w*z[11]
           + a3.x*z[12] + a3.y*z[13] + a3.z*z[14] + a3.w*z[15];
    }
  }

  // ---- half 1: rotate P -> R P R (R = Ri^T Rj) ----
  if (hf){
    const float* Ri = frames + (size_t)col*9;
    const float* Rj = frames + (size_t)row*9;
    float R[9];
    #pragma unroll
    for (int i = 0; i < 3; ++i)
      #pragma unroll
      for (int j = 0; j < 3; ++j)
        R[i*3+j] = Ri[i]*Rj[j] + Ri[3+i]*Rj[3+j] + Ri[6+i]*Rj[6+j];
    float A[9];
    #pragma unroll
    for (int i = 0; i < 3; ++i)
      #pragma unroll
      for (int j = 0; j < 3; ++j)
        A[i*3+j] = R[i*3+0]*P[0+j] + R[i*3+1]*P[3+j] + R[i*3+2]*P[6+j];
    #pragma unroll
    for (int i = 0; i < 3; ++i)
      #pragma unroll
      for (int j = 0; j < 3; ++j)
        P[i*3+j] = A[i*3+0]*R[0+j] + A[i*3+1]*R[3+j] + A[i*3+2]*R[6+j];
  }

  // ---- combine halves: o = P_half0 + P_half1 ----
  #pragma unroll
  for (int m = 0; m < 9; ++m) P[m] += __shfl_xor(P[m], 16);

  if (hf == 0){
    float s01 = 0.5f*(P[1]+P[3]), s02 = 0.5f*(P[2]+P[6]), s12 = 0.5f*(P[5]+P[7]);
    uint32* tp = tn + (size_t)e*48 + c*3;
    tp[0] = pk2(P[0], s01);
    tp[1] = pk2(s02, P[4]);
    tp[2] = pk2(s12, P[8]);
  }
}

// ---------------- segsum: thread per (node, channel); sequential CSR-range sum ----------------
__global__ __launch_bounds__(256) void segsum_k(
    const uint32* __restrict__ tn, const uint32* __restrict__ start,
    float* __restrict__ out)
{
  int tid = blockIdx.x*256 + threadIdx.x;
  if (tid >= NN*16) return;
  int n = tid >> 4, c = tid & 15;
  uint32 beg = (n == 0) ? 0u : start[n-1];
  uint32 end = start[n];

  float a0=0.f, a1=0.f, a2=0.f, a3=0.f, a4=0.f, a5=0.f;
  for (uint32 i = beg; i < end; ++i){
    const uint32* tp = tn + (size_t)i*48 + c*3;
    uint32 x0 = tp[0], x1 = tp[1], x2 = tp[2];
    a0 += bflo(x0); a1 += bfhi(x0);
    a2 += bflo(x1); a3 += bfhi(x1);
    a4 += bflo(x2); a5 += bfhi(x2);
  }

  float* op = out + (size_t)n*144 + c*9;
  op[0] = a0; op[1] = a1; op[2] = a2;
  op[3] = a1; op[4] = a3; op[5] = a4;
  op[6] = a2; op[7] = a4; op[8] = a5;
}

extern "C" void kernel_launch(void* const* d_in, const int* in_sizes, int n_in,
                              void* d_out, int out_size, void* d_ws, size_t ws_size,
                              hipStream_t stream) {
    const float* h      = (const float*)d_in[1];
    const float* frames = (const float*)d_in[2];
    const int*   ei     = (const int*)d_in[3];
    const float* W1  = (const float*)d_in[5];
    const float* b1  = (const float*)d_in[6];
    const float* g1  = (const float*)d_in[7];
    const float* be1 = (const float*)d_in[8];
    const float* W2  = (const float*)d_in[9];
    const float* b2  = (const float*)d_in[10];
    const float* g2  = (const float*)d_in[11];
    const float* be2 = (const float*)d_in[12];
    const float* Wi  = (const float*)d_in[13];
    const float* bi  = (const float*)d_in[14];
    const float* gi  = (const float*)d_in[15];
    const float* bei = (const float*)d_in[16];

    float* out = (float*)d_out;

    // ws layout (138.33 MB <= proven 140.68 MB):
    u16*    uu_t  = (u16*)d_ws;                             // [N,512] bf16: 30,720,000
    u16*    v16_t = (u16*)  ((char*)d_ws + 30720000);       // [N,512] bf16: 30,720,000
    float*  tens_t= (float*)((char*)d_ws + 61440000);       // [N,144] f32 : 17,280,000
    u16*    Wq    = (u16*)  ((char*)d_ws + 78720000);       // 524,288
    u16*    W1s   = (u16*)  ((char*)d_ws + 79244288);       // 73,728
    u16*    W2s   = (u16*)  ((char*)d_ws + 79318016);       // 92,160
    float*  gt    = (float*)((char*)d_ws + 79410176);       // 2,048
    float*  bet   = (float*)((char*)d_ws + 79412224);       // 2,048
    uint32* start = (uint32*)((char*)d_ws + 79414272);      // 120,000
    u16*    srow  = (u16*)  ((char*)d_ws + 79534272);       // 600,000
    u16*    scol  = (u16*)  ((char*)d_ws + 80134272);       // 600,000
    uint32* tn    = (uint32*)((char*)d_ws + 80734272);      // [E,16,3] u32 (bf16x2): 57,600,000

    hipMemsetAsync(start, 0, NN * sizeof(uint32), stream);

    cvt_all_k<<<256, 256, 0, stream>>>(Wi, Wq, W1, W1s, W2, W2s, gi, bei, gt, bet);
    node_all_k<<<NN/16, 256, 0, stream>>>(h, Wq, bi, W1s, W2s, b1, g1, be1, b2, g2, be2,
                                          uu_t, v16_t, tens_t);
    hist_k<<<(EE + 255)/256, 256, 0, stream>>>(ei, start);
    scan_k<<<1, 1024, 0, stream>>>(start);
    scatter_k<<<(EE + 255)/256, 256, 0, stream>>>(ei, start, srow, scol);
    edge_par_k<<<EE/8, 256, 0, stream>>>(uu_t, v16_t, frames, tens_t, gt, bet, srow, scol, tn);
    segsum_k<<<(NN*16 + 255)/256, 256, 0, stream>>>(tn, start, out);
}